// Round 13
// baseline (213.396 us; speedup 1.0000x reference)
//
#include <hip/hip_runtime.h>
#include <math.h>

namespace {
constexpr int kB   = 32;
constexpr int kIDF = 128;
constexpr int kCDF = 256;
constexpr int kSL  = 24;
constexpr int kQL  = 128 * 128;
constexpr int kThreads = 512;              // 512-lane contiguous window
constexpr int kQPT = 4;                    // q per thread (float4 path)
constexpr int kQPB = kThreads * kQPT;      // 2048 q per block -> 256 blocks

typedef float f32x4 __attribute__((ext_vector_type(4)));

// sourceT[b,i,l] = sum_c W[i,c] * context[b,c,l]
__global__ __launch_bounds__(256) void proj_kernel(
    const float* __restrict__ W, const float* __restrict__ ctx,
    float* __restrict__ sT_out) {
  const int b = blockIdx.x;
  __shared__ float ctxs[kCDF * kSL];
  const float* ctxb = ctx + (size_t)b * kCDF * kSL;
  for (int t = threadIdx.x; t < kCDF * kSL; t += 256) ctxs[t] = ctxb[t];
  __syncthreads();
  #pragma unroll
  for (int k = 0; k < (kIDF * kSL) / 256; ++k) {
    const int o = threadIdx.x + k * 256;
    const int i = o / kSL, l = o % kSL;
    const float* wrow = W + i * kCDF;
    float acc = 0.f;
    #pragma unroll 8
    for (int c = 0; c < kCDF; ++c) acc = fmaf(wrow[c], ctxs[c * kSL + l], acc);
    sT_out[(size_t)b * kIDF * kSL + o] = acc;
  }
}

// Main attention kernel (r12 structure: 512-thread blocks, 8KB contiguous
// runs, scalar-sT s_load, 1 block/CU). SINGLE CHANGE vs r12: plain stores
// instead of __builtin_nontemporal_store — A/B test of the NT write path.
// NT stores bypass L2/L3 write-combining; the 6.3-6.9 TB/s reference
// streams all use normal stores. NT entered at r3/r4 bundled with QPT=4
// and was never isolated; write-path cost is invisible to SQ counters.
__global__ __launch_bounds__(kThreads) void attn_scalar(
    const float* __restrict__ input, const float* __restrict__ sT_in,
    const int* __restrict__ mask, float* __restrict__ out_wc,
    float* __restrict__ out_attn) {
  const int b  = blockIdx.y;
  const int q0 = blockIdx.x * kQPB + threadIdx.x * kQPT;
  const float* __restrict__ sTb = sT_in + (size_t)b * kIDF * kSL;

  // mask bit set == position masked with -inf (weight 0)
  unsigned mbits = 0;
  #pragma unroll
  for (int l = 0; l < kSL; ++l) mbits |= (mask[b * kSL + l] ? 1u : 0u) << l;

  f32x4 acc[kSL];
  #pragma unroll
  for (int l = 0; l < kSL; ++l) acc[l] = (f32x4)0.f;

  // attn[b,q,l] = sum_i input[b,i,q] * sT[i,l]
  const float* inb = input + (size_t)b * kIDF * kQL + q0;
  #pragma unroll 1
  for (int ii = 0; ii < kIDF; ii += 8) {
    f32x4 t[8];
    #pragma unroll
    for (int u = 0; u < 8; ++u)
      t[u] = *reinterpret_cast<const f32x4*>(inb + (size_t)(ii + u) * kQL);
    #pragma unroll
    for (int u = 0; u < 8; ++u) {
      const float* wrow = sTb + (ii + u) * kSL;  // uniform -> s_load
      #pragma unroll
      for (int l = 0; l < kSL; ++l) acc[l] += t[u] * wrow[l];
    }
  }

  // masked softmax over l (24), per q-component
  {
    float m[4] = {-INFINITY, -INFINITY, -INFINITY, -INFINITY};
    #pragma unroll
    for (int l = 0; l < kSL; ++l)
      if (!((mbits >> l) & 1u)) {
        #pragma unroll
        for (int c = 0; c < 4; ++c) m[c] = fmaxf(m[c], acc[l][c]);
      }
    float s[4] = {0.f, 0.f, 0.f, 0.f};
    #pragma unroll
    for (int l = 0; l < kSL; ++l) {
      const bool km = (mbits >> l) & 1u;
      #pragma unroll
      for (int c = 0; c < 4; ++c) {
        const float p = km ? 0.f : __expf(acc[l][c] - m[c]);
        acc[l][c] = p;
        s[c] += p;
      }
    }
    f32x4 r;
    #pragma unroll
    for (int c = 0; c < 4; ++c) r[c] = 1.f / s[c];
    #pragma unroll
    for (int l = 0; l < kSL; ++l) acc[l] *= r;
  }

  // attn_out[b,l,q] — plain stores (L2 write-combining path)
  float* oa = out_attn + (size_t)b * kSL * kQL + q0;
  #pragma unroll
  for (int l = 0; l < kSL; ++l)
    *reinterpret_cast<f32x4*>(oa + (size_t)l * kQL) = acc[l];

  // weightedContext[b,i,q] = sum_l sT[i,l] * attn[b,q,l]
  float* ow = out_wc + (size_t)b * kIDF * kQL + q0;
  #pragma unroll 1
  for (int ii = 0; ii < kIDF; ii += 8) {
    f32x4 res[8];
    #pragma unroll
    for (int u = 0; u < 8; ++u) res[u] = (f32x4)0.f;
    #pragma unroll
    for (int u = 0; u < 8; ++u) {
      const float* wrow = sTb + (ii + u) * kSL;  // uniform -> s_load (cached)
      #pragma unroll
      for (int l = 0; l < kSL; ++l) res[u] += acc[l] * wrow[l];
    }
    #pragma unroll
    for (int u = 0; u < 8; ++u)
      *reinterpret_cast<f32x4*>(ow + (size_t)(ii + u) * kQL) = res[u];
  }
}

// Fallback (no workspace): compute sourceT per block in LDS.
__global__ __launch_bounds__(kThreads) void attn_fused(
    const float* __restrict__ input, const float* __restrict__ W,
    const float* __restrict__ ctx, const int* __restrict__ mask,
    float* __restrict__ out_wc, float* __restrict__ out_attn) {
  const int b  = blockIdx.y;
  const int q0 = blockIdx.x * kQPB + threadIdx.x * kQPT;
  constexpr int kSTN = kIDF * kSL;
  __shared__ float smem[kSTN + kCDF * kSL];
  float* sT = smem;
  {
    float* ctxs = smem + kSTN;
    const float* ctxb = ctx + (size_t)b * kCDF * kSL;
    for (int t = threadIdx.x; t < kCDF * kSL; t += kThreads) ctxs[t] = ctxb[t];
    __syncthreads();
    for (int k = threadIdx.x; k < kSTN; k += kThreads) {
      const int i = k / kSL, l = k % kSL;
      const float* wrow = W + i * kCDF;
      float a = 0.f;
      for (int c = 0; c < kCDF; ++c) a = fmaf(wrow[c], ctxs[c * kSL + l], a);
      sT[k] = a;
    }
  }
  __syncthreads();

  unsigned mbits = 0;
  #pragma unroll
  for (int l = 0; l < kSL; ++l) mbits |= (mask[b * kSL + l] ? 1u : 0u) << l;

  f32x4 acc[kSL];
  #pragma unroll
  for (int l = 0; l < kSL; ++l) acc[l] = (f32x4)0.f;

  const float* inb = input + (size_t)b * kIDF * kQL + q0;
  #pragma unroll 1
  for (int ii = 0; ii < kIDF; ii += 8) {
    f32x4 t[8];
    #pragma unroll
    for (int u = 0; u < 8; ++u)
      t[u] = *reinterpret_cast<const f32x4*>(inb + (size_t)(ii + u) * kQL);
    #pragma unroll
    for (int u = 0; u < 8; ++u) {
      const float* wrow = &sT[(ii + u) * kSL];
      #pragma unroll
      for (int l = 0; l < kSL; ++l) acc[l] += t[u] * wrow[l];
    }
  }

  {
    float m[4] = {-INFINITY, -INFINITY, -INFINITY, -INFINITY};
    #pragma unroll
    for (int l = 0; l < kSL; ++l)
      if (!((mbits >> l) & 1u)) {
        #pragma unroll
        for (int c = 0; c < 4; ++c) m[c] = fmaxf(m[c], acc[l][c]);
      }
    float s[4] = {0.f, 0.f, 0.f, 0.f};
    #pragma unroll
    for (int l = 0; l < kSL; ++l) {
      const bool km = (mbits >> l) & 1u;
      #pragma unroll
      for (int c = 0; c < 4; ++c) {
        const float p = km ? 0.f : __expf(acc[l][c] - m[c]);
        acc[l][c] = p;
        s[c] += p;
      }
    }
    f32x4 r;
    #pragma unroll
    for (int c = 0; c < 4; ++c) r[c] = 1.f / s[c];
    #pragma unroll
    for (int l = 0; l < kSL; ++l) acc[l] *= r;
  }

  float* oa = out_attn + (size_t)b * kSL * kQL + q0;
  #pragma unroll
  for (int l = 0; l < kSL; ++l)
    *reinterpret_cast<f32x4*>(oa + (size_t)l * kQL) = acc[l];

  float* ow = out_wc + (size_t)b * kIDF * kQL + q0;
  #pragma unroll 1
  for (int ii = 0; ii < kIDF; ii += 8) {
    f32x4 res[8];
    #pragma unroll
    for (int u = 0; u < 8; ++u) res[u] = (f32x4)0.f;
    #pragma unroll
    for (int u = 0; u < 8; ++u) {
      const float* wrow = &sT[(ii + u) * kSL];
      #pragma unroll
      for (int l = 0; l < kSL; ++l) res[u] += acc[l] * wrow[l];
    }
    #pragma unroll
    for (int u = 0; u < 8; ++u)
      *reinterpret_cast<f32x4*>(ow + (size_t)(ii + u) * kQL) = res[u];
  }
}
}  // namespace

extern "C" void kernel_launch(void* const* d_in, const int* in_sizes, int n_in,
                              void* d_out, int out_size, void* d_ws, size_t ws_size,
                              hipStream_t stream) {
  const float* input = (const float*)d_in[0];
  const float* ctx   = (const float*)d_in[1];
  const float* W     = (const float*)d_in[2];
  const int*   mask  = (const int*)d_in[3];
  float* out_wc   = (float*)d_out;
  float* out_attn = (float*)d_out + (size_t)kB * kIDF * kQL;

  const size_t st_bytes = (size_t)kB * kIDF * kSL * sizeof(float);
  dim3 grid(kQL / kQPB, kB);
  if (ws_size >= st_bytes) {
    float* sT = (float*)d_ws;
    proj_kernel<<<kB, 256, 0, stream>>>(W, ctx, sT);
    attn_scalar<<<grid, kThreads, 0, stream>>>(input, sT, mask, out_wc, out_attn);
  } else {
    attn_fused<<<grid, kThreads, 0, stream>>>(input, W, ctx, mask, out_wc, out_attn);
  }
}

// Round 14
// 149.522 us; speedup vs baseline: 1.4272x; 1.4272x over previous
//
#include <hip/hip_runtime.h>
#include <math.h>

namespace {
constexpr int kB   = 32;
constexpr int kIDF = 128;
constexpr int kCDF = 256;
constexpr int kSL  = 24;
constexpr int kQL  = 128 * 128;
constexpr int kThreads = 512;              // 512-lane contiguous window
constexpr int kQPT = 4;                    // q per thread (float4 path)
constexpr int kQPB = kThreads * kQPT;      // 2048 q per block -> 256 blocks

typedef float f32x4 __attribute__((ext_vector_type(4)));

// sourceT[b,i,l] = sum_c W[i,c] * context[b,c,l]
__global__ __launch_bounds__(256) void proj_kernel(
    const float* __restrict__ W, const float* __restrict__ ctx,
    float* __restrict__ sT_out) {
  const int b = blockIdx.x;
  __shared__ float ctxs[kCDF * kSL];
  const float* ctxb = ctx + (size_t)b * kCDF * kSL;
  for (int t = threadIdx.x; t < kCDF * kSL; t += 256) ctxs[t] = ctxb[t];
  __syncthreads();
  #pragma unroll
  for (int k = 0; k < (kIDF * kSL) / 256; ++k) {
    const int o = threadIdx.x + k * 256;
    const int i = o / kSL, l = o % kSL;
    const float* wrow = W + i * kCDF;
    float acc = 0.f;
    #pragma unroll 8
    for (int c = 0; c < kCDF; ++c) acc = fmaf(wrow[c], ctxs[c * kSL + l], acc);
    sT_out[(size_t)b * kIDF * kSL + o] = acc;
  }
}

// Main attention kernel (r12 structure: 512-thread blocks, 8KB contiguous
// runs, scalar-sT s_load, 1 block/CU, NT stores — NT stores are a
// confirmed +29% win, r13 reverse-test). SINGLE CHANGE vs r12:
// __builtin_nontemporal_load on the input stream. Input lines are
// single-use within the kernel (cross-replay reuse lives in L3, which NT
// hints don't bypass); evict-first marking spares L2 the 268MB of
// dead-line pollution — symmetric to what NT did for the write path.
__global__ __launch_bounds__(kThreads) void attn_scalar(
    const float* __restrict__ input, const float* __restrict__ sT_in,
    const int* __restrict__ mask, float* __restrict__ out_wc,
    float* __restrict__ out_attn) {
  const int b  = blockIdx.y;
  const int q0 = blockIdx.x * kQPB + threadIdx.x * kQPT;
  const float* __restrict__ sTb = sT_in + (size_t)b * kIDF * kSL;

  // mask bit set == position masked with -inf (weight 0)
  unsigned mbits = 0;
  #pragma unroll
  for (int l = 0; l < kSL; ++l) mbits |= (mask[b * kSL + l] ? 1u : 0u) << l;

  f32x4 acc[kSL];
  #pragma unroll
  for (int l = 0; l < kSL; ++l) acc[l] = (f32x4)0.f;

  // attn[b,q,l] = sum_i input[b,i,q] * sT[i,l]
  const float* inb = input + (size_t)b * kIDF * kQL + q0;
  #pragma unroll 1
  for (int ii = 0; ii < kIDF; ii += 8) {
    f32x4 t[8];
    #pragma unroll
    for (int u = 0; u < 8; ++u)
      t[u] = __builtin_nontemporal_load(
          reinterpret_cast<const f32x4*>(inb + (size_t)(ii + u) * kQL));
    #pragma unroll
    for (int u = 0; u < 8; ++u) {
      const float* wrow = sTb + (ii + u) * kSL;  // uniform -> s_load
      #pragma unroll
      for (int l = 0; l < kSL; ++l) acc[l] += t[u] * wrow[l];
    }
  }

  // masked softmax over l (24), per q-component
  {
    float m[4] = {-INFINITY, -INFINITY, -INFINITY, -INFINITY};
    #pragma unroll
    for (int l = 0; l < kSL; ++l)
      if (!((mbits >> l) & 1u)) {
        #pragma unroll
        for (int c = 0; c < 4; ++c) m[c] = fmaxf(m[c], acc[l][c]);
      }
    float s[4] = {0.f, 0.f, 0.f, 0.f};
    #pragma unroll
    for (int l = 0; l < kSL; ++l) {
      const bool km = (mbits >> l) & 1u;
      #pragma unroll
      for (int c = 0; c < 4; ++c) {
        const float p = km ? 0.f : __expf(acc[l][c] - m[c]);
        acc[l][c] = p;
        s[c] += p;
      }
    }
    f32x4 r;
    #pragma unroll
    for (int c = 0; c < 4; ++c) r[c] = 1.f / s[c];
    #pragma unroll
    for (int l = 0; l < kSL; ++l) acc[l] *= r;
  }

  // attn_out[b,l,q] — NT stores (confirmed +29% win)
  float* oa = out_attn + (size_t)b * kSL * kQL + q0;
  #pragma unroll
  for (int l = 0; l < kSL; ++l)
    __builtin_nontemporal_store(acc[l], reinterpret_cast<f32x4*>(oa + (size_t)l * kQL));

  // weightedContext[b,i,q] = sum_l sT[i,l] * attn[b,q,l]
  float* ow = out_wc + (size_t)b * kIDF * kQL + q0;
  #pragma unroll 1
  for (int ii = 0; ii < kIDF; ii += 8) {
    f32x4 res[8];
    #pragma unroll
    for (int u = 0; u < 8; ++u) res[u] = (f32x4)0.f;
    #pragma unroll
    for (int u = 0; u < 8; ++u) {
      const float* wrow = sTb + (ii + u) * kSL;  // uniform -> s_load (cached)
      #pragma unroll
      for (int l = 0; l < kSL; ++l) res[u] += acc[l] * wrow[l];
    }
    #pragma unroll
    for (int u = 0; u < 8; ++u)
      __builtin_nontemporal_store(res[u],
          reinterpret_cast<f32x4*>(ow + (size_t)(ii + u) * kQL));
  }
}

// Fallback (no workspace): compute sourceT per block in LDS.
__global__ __launch_bounds__(kThreads) void attn_fused(
    const float* __restrict__ input, const float* __restrict__ W,
    const float* __restrict__ ctx, const int* __restrict__ mask,
    float* __restrict__ out_wc, float* __restrict__ out_attn) {
  const int b  = blockIdx.y;
  const int q0 = blockIdx.x * kQPB + threadIdx.x * kQPT;
  constexpr int kSTN = kIDF * kSL;
  __shared__ float smem[kSTN + kCDF * kSL];
  float* sT = smem;
  {
    float* ctxs = smem + kSTN;
    const float* ctxb = ctx + (size_t)b * kCDF * kSL;
    for (int t = threadIdx.x; t < kCDF * kSL; t += kThreads) ctxs[t] = ctxb[t];
    __syncthreads();
    for (int k = threadIdx.x; k < kSTN; k += kThreads) {
      const int i = k / kSL, l = k % kSL;
      const float* wrow = W + i * kCDF;
      float a = 0.f;
      for (int c = 0; c < kCDF; ++c) a = fmaf(wrow[c], ctxs[c * kSL + l], a);
      sT[k] = a;
    }
  }
  __syncthreads();

  unsigned mbits = 0;
  #pragma unroll
  for (int l = 0; l < kSL; ++l) mbits |= (mask[b * kSL + l] ? 1u : 0u) << l;

  f32x4 acc[kSL];
  #pragma unroll
  for (int l = 0; l < kSL; ++l) acc[l] = (f32x4)0.f;

  const float* inb = input + (size_t)b * kIDF * kQL + q0;
  #pragma unroll 1
  for (int ii = 0; ii < kIDF; ii += 8) {
    f32x4 t[8];
    #pragma unroll
    for (int u = 0; u < 8; ++u)
      t[u] = *reinterpret_cast<const f32x4*>(inb + (size_t)(ii + u) * kQL);
    #pragma unroll
    for (int u = 0; u < 8; ++u) {
      const float* wrow = &sT[(ii + u) * kSL];
      #pragma unroll
      for (int l = 0; l < kSL; ++l) acc[l] += t[u] * wrow[l];
    }
  }

  {
    float m[4] = {-INFINITY, -INFINITY, -INFINITY, -INFINITY};
    #pragma unroll
    for (int l = 0; l < kSL; ++l)
      if (!((mbits >> l) & 1u)) {
        #pragma unroll
        for (int c = 0; c < 4; ++c) m[c] = fmaxf(m[c], acc[l][c]);
      }
    float s[4] = {0.f, 0.f, 0.f, 0.f};
    #pragma unroll
    for (int l = 0; l < kSL; ++l) {
      const bool km = (mbits >> l) & 1u;
      #pragma unroll
      for (int c = 0; c < 4; ++c) {
        const float p = km ? 0.f : __expf(acc[l][c] - m[c]);
        acc[l][c] = p;
        s[c] += p;
      }
    }
    f32x4 r;
    #pragma unroll
    for (int c = 0; c < 4; ++c) r[c] = 1.f / s[c];
    #pragma unroll
    for (int l = 0; l < kSL; ++l) acc[l] *= r;
  }

  float* oa = out_attn + (size_t)b * kSL * kQL + q0;
  #pragma unroll
  for (int l = 0; l < kSL; ++l)
    __builtin_nontemporal_store(acc[l], reinterpret_cast<f32x4*>(oa + (size_t)l * kQL));

  float* ow = out_wc + (size_t)b * kIDF * kQL + q0;
  #pragma unroll 1
  for (int ii = 0; ii < kIDF; ii += 8) {
    f32x4 res[8];
    #pragma unroll
    for (int u = 0; u < 8; ++u) res[u] = (f32x4)0.f;
    #pragma unroll
    for (int u = 0; u < 8; ++u) {
      const float* wrow = &sT[(ii + u) * kSL];
      #pragma unroll
      for (int l = 0; l < kSL; ++l) res[u] += acc[l] * wrow[l];
    }
    #pragma unroll
    for (int u = 0; u < 8; ++u)
      __builtin_nontemporal_store(res[u],
          reinterpret_cast<f32x4*>(ow + (size_t)(ii + u) * kQL));
  }
}
}  // namespace

extern "C" void kernel_launch(void* const* d_in, const int* in_sizes, int n_in,
                              void* d_out, int out_size, void* d_ws, size_t ws_size,
                              hipStream_t stream) {
  const float* input = (const float*)d_in[0];
  const float* ctx   = (const float*)d_in[1];
  const float* W     = (const float*)d_in[2];
  const int*   mask  = (const int*)d_in[3];
  float* out_wc   = (float*)d_out;
  float* out_attn = (float*)d_out + (size_t)kB * kIDF * kQL;

  const size_t st_bytes = (size_t)kB * kIDF * kSL * sizeof(float);
  dim3 grid(kQL / kQPB, kB);
  if (ws_size >= st_bytes) {
    float* sT = (float*)d_ws;
    proj_kernel<<<kB, 256, 0, stream>>>(W, ctx, sT);
    attn_scalar<<<grid, kThreads, 0, stream>>>(input, sT, mask, out_wc, out_attn);
  } else {
    attn_fused<<<grid, kThreads, 0, stream>>>(input, W, ctx, mask, out_wc, out_attn);
  }
}